// Round 7
// baseline (174.808 us; speedup 1.0000x reference)
//
#include <hip/hip_runtime.h>
#include <math.h>

#define B_ 8
#define N_ 128
#define M_ 256
#define F_ 256

#define LOG2E2 2.8853900817779268f  // 2*log2(e)

// ---------------------------------------------------------------------------
// Single fused kernel, 256 blocks x 512 threads (1 block/CU), last-block-done.
//
// Block (b = bid>>5, nc = bid&31) owns n rows n0=nc*4 .. n0+3, ALL 256 m,
// ALL 256 f.  Wave w = f-chunk fc (32 f each, 8*32 = 256 total).
// Lane covers 4 m: m = k*64 + lane, k = 0..3.
//
// A1: us[r][g] = (x[r,:].Uw[g,:] + Ub[g])*2log2e  in LDS (threads 0..255;
//     x rows block-uniform -> scalar loads, Uw per-lane coalesced).
// A2: S[n][m] = sum_f Ww[f] * rcp(exp2(us[n][f]*y[m][f]) + 1)
//     y chunk register-resident (yv[4][8] float4), Ww chunk wave-uniform ->
//     SGPR, us read as LDS broadcast. Hot loop: registers only.
//     alpha = Wsum - 2S is monotone-decreasing in S => reduce MIN of S;
//     Wsum and W_b cancel in max/softmax (shift-invariant).
//     Cross-fc sum via LDS red[4][8][256]; then
//     rowminS[b][n] = min over all 256 m (FINAL), cpartS[b][nc][m] over 4 n.
// ticket: threadfence + atomicAdd; ticket==255 block runs phase B for all b.
// B:  two softmaxes of (-2 * minS) + pooled dots -> out[B][512].
// ---------------------------------------------------------------------------
__global__ __launch_bounds__(512, 2) void fused_all(
    const float* __restrict__ x, const float* __restrict__ y,
    const float* __restrict__ Uw, const float* __restrict__ Ub,
    const float* __restrict__ Ww,
    float* __restrict__ rowminS, float* __restrict__ cpartS,
    unsigned* __restrict__ counter, float* __restrict__ out) {
  __shared__ float us[4][F_];          //  4 KB
  __shared__ float red[4][8][256];     // 32 KB  [n][fc][m]
  __shared__ float sm[4][256];         //  4 KB
  __shared__ float xw[N_];
  __shared__ float yw[M_];
  __shared__ float bred[8];
  __shared__ float part[2][256];
  __shared__ unsigned ticket_s;

  const int tid  = threadIdx.x;
  const int bid  = blockIdx.x;
  const int b    = bid >> 5;
  const int nc   = bid & 31;
  const int n0   = nc * 4;
  const int lane = tid & 63;
  const int w    = tid >> 6;
  const int fc   = __builtin_amdgcn_readfirstlane(w);   // 0..7, 32 f each

  // ---- A1: 4 local u rows (threads 0..255) ----
  if (tid < 256) {
    const int g = tid;
    const float* __restrict__ uwr = Uw + (size_t)g * F_;
    const float* __restrict__ xr  = x + (size_t)(b * N_ + n0) * F_; // uniform
    float a0 = 0.f, a1 = 0.f, a2 = 0.f, a3 = 0.f;
#pragma unroll 4
    for (int f = 0; f < F_; f += 4) {
      const float4 wv = *(const float4*)&uwr[f];
      const float4 x0 = *(const float4*)&xr[0 * F_ + f];
      const float4 x1 = *(const float4*)&xr[1 * F_ + f];
      const float4 x2 = *(const float4*)&xr[2 * F_ + f];
      const float4 x3 = *(const float4*)&xr[3 * F_ + f];
      a0 = fmaf(wv.x, x0.x, a0); a0 = fmaf(wv.y, x0.y, a0);
      a0 = fmaf(wv.z, x0.z, a0); a0 = fmaf(wv.w, x0.w, a0);
      a1 = fmaf(wv.x, x1.x, a1); a1 = fmaf(wv.y, x1.y, a1);
      a1 = fmaf(wv.z, x1.z, a1); a1 = fmaf(wv.w, x1.w, a1);
      a2 = fmaf(wv.x, x2.x, a2); a2 = fmaf(wv.y, x2.y, a2);
      a2 = fmaf(wv.z, x2.z, a2); a2 = fmaf(wv.w, x2.w, a2);
      a3 = fmaf(wv.x, x3.x, a3); a3 = fmaf(wv.y, x3.y, a3);
      a3 = fmaf(wv.z, x3.z, a3); a3 = fmaf(wv.w, x3.w, a3);
    }
    const float ubv = Ub[g];
    us[0][g] = (a0 + ubv) * LOG2E2;
    us[1][g] = (a1 + ubv) * LOG2E2;
    us[2][g] = (a2 + ubv) * LOG2E2;
    us[3][g] = (a3 + ubv) * LOG2E2;
  }

  // ---- per-thread register staging (after A1 compute, overlaps barrier) ----
  float4 yv[4][8];     // 4 m-values x 32 f  (128 VGPRs)
  float4 wwv[8];       // wave-uniform -> SGPR
#pragma unroll
  for (int k = 0; k < 4; ++k) {
    const float* yr = y + ((size_t)(b * M_ + k * 64 + lane)) * F_ + fc * 32;
#pragma unroll
    for (int j = 0; j < 8; ++j) yv[k][j] = *(const float4*)&yr[4 * j];
  }
  {
    const float* wr = Ww + fc * 32;
#pragma unroll
    for (int j = 0; j < 8; ++j) wwv[j] = *(const float4*)&wr[4 * j];
  }
  __syncthreads();

  // ---- A2: register-resident hot loop ----
  float acc[4][4] = {};   // [n][k]
#pragma unroll
  for (int n = 0; n < 4; ++n) {
    float4 uv[8];
#pragma unroll
    for (int j = 0; j < 8; ++j)
      uv[j] = *(const float4*)&us[n][fc * 32 + 4 * j];  // LDS broadcast
#pragma unroll
    for (int k = 0; k < 4; ++k) {
      float s0 = 0.f, s1 = 0.f;
#pragma unroll
      for (int j = 0; j < 8; ++j) {
        s0 = fmaf(wwv[j].x, __builtin_amdgcn_rcpf(__builtin_amdgcn_exp2f(uv[j].x * yv[k][j].x) + 1.f), s0);
        s1 = fmaf(wwv[j].y, __builtin_amdgcn_rcpf(__builtin_amdgcn_exp2f(uv[j].y * yv[k][j].y) + 1.f), s1);
        s0 = fmaf(wwv[j].z, __builtin_amdgcn_rcpf(__builtin_amdgcn_exp2f(uv[j].z * yv[k][j].z) + 1.f), s0);
        s1 = fmaf(wwv[j].w, __builtin_amdgcn_rcpf(__builtin_amdgcn_exp2f(uv[j].w * yv[k][j].w) + 1.f), s1);
      }
      acc[n][k] = s0 + s1;
    }
  }

  // ---- cross-fc sum via LDS ----
#pragma unroll
  for (int n = 0; n < 4; ++n)
#pragma unroll
    for (int k = 0; k < 4; ++k)
      red[n][fc][k * 64 + lane] = acc[n][k];
  __syncthreads();

#pragma unroll
  for (int p = tid; p < 1024; p += 512) {
    const int n = p >> 8, mm = p & 255;
    float s = 0.f;
#pragma unroll
    for (int k = 0; k < 8; ++k) s += red[n][k][mm];
    sm[n][mm] = s;
  }
  __syncthreads();

  if (w < 4) {
    // rowmin over all 256 m for n = w  (FINAL)
    float v = fminf(fminf(sm[w][lane], sm[w][lane + 64]),
                    fminf(sm[w][lane + 128], sm[w][lane + 192]));
#pragma unroll
    for (int s = 32; s; s >>= 1) v = fminf(v, __shfl_xor(v, s));
    if (lane == 0) rowminS[b * N_ + n0 + w] = v;
  } else {
    // colmin over the block's 4 n for this m-quarter
    const int mq = (w - 4) * 64 + lane;
    const float c = fminf(fminf(sm[0][mq], sm[1][mq]),
                          fminf(sm[2][mq], sm[3][mq]));
    cpartS[((size_t)b * 32 + nc) * M_ + mq] = c;
  }

  // ---- last-block-done ticket ----
  __threadfence();                 // release this block's partials
  __syncthreads();
  if (tid == 0) ticket_s = atomicAdd(counter, 1u);
  __syncthreads();
  if (ticket_s != 255u) return;
  __threadfence();                 // acquire all blocks' partials

  // ---- Phase B: all batches, one block ----
  for (int bb = 0; bb < B_; ++bb) {
    // x attention: softmax over n of (-2 * rowminS)
    const float rv = (tid < N_) ? -2.f * rowminS[bb * N_ + tid] : -INFINITY;
    float m1 = rv;
#pragma unroll
    for (int s = 32; s; s >>= 1) m1 = fmaxf(m1, __shfl_xor(m1, s));
    if (lane == 0) bred[w] = m1;
    __syncthreads();
    m1 = bred[0];
#pragma unroll
    for (int k = 1; k < 8; ++k) m1 = fmaxf(m1, bred[k]);
    __syncthreads();
    const float e1 = (tid < N_) ? __expf(rv - m1) : 0.f;
    float s1 = e1;
#pragma unroll
    for (int s = 32; s; s >>= 1) s1 += __shfl_xor(s1, s);
    if (lane == 0) bred[w] = s1;
    __syncthreads();
    s1 = bred[0] + bred[1] + bred[2] + bred[3] +
         bred[4] + bred[5] + bred[6] + bred[7];
    if (tid < N_) xw[tid] = e1 / s1;
    __syncthreads();

    // y attention: softmax over m of (-2 * min over 32 nc partials)
    float cv = -INFINITY;
    if (tid < M_) {
      float c = INFINITY;
#pragma unroll 8
      for (int k = 0; k < 32; ++k)
        c = fminf(c, cpartS[((size_t)bb * 32 + k) * M_ + tid]);
      cv = -2.f * c;
    }
    float m2 = cv;
#pragma unroll
    for (int s = 32; s; s >>= 1) m2 = fmaxf(m2, __shfl_xor(m2, s));
    if (lane == 0) bred[w] = m2;
    __syncthreads();
    m2 = bred[0];
#pragma unroll
    for (int k = 1; k < 8; ++k) m2 = fmaxf(m2, bred[k]);
    __syncthreads();
    const float e2 = (tid < M_) ? __expf(cv - m2) : 0.f;
    float s2 = e2;
#pragma unroll
    for (int s = 32; s; s >>= 1) s2 += __shfl_xor(s2, s);
    if (lane == 0) bred[w] = s2;
    __syncthreads();
    s2 = bred[0] + bred[1] + bred[2] + bred[3] +
         bred[4] + bred[5] + bred[6] + bred[7];
    if (tid < M_) yw[tid] = e2 / s2;
    __syncthreads();

    // pooled outputs, 2-way split over the sum dimension
    const int q = tid >> 8;     // 0..1
    const int f = tid & 255;
    float accx = 0.f;
#pragma unroll 4
    for (int n = q; n < N_; n += 2)
      accx = fmaf(xw[n], x[(size_t)(bb * N_ + n) * F_ + f], accx);
    part[q][f] = accx;
    __syncthreads();
    if (tid < 256) out[bb * (2 * F_) + f] = part[0][f] + part[1][f];
    __syncthreads();
    float accy = 0.f;
#pragma unroll 4
    for (int mm = q; mm < M_; mm += 2)
      accy = fmaf(yw[mm], y[(size_t)(bb * M_ + mm) * F_ + f], accy);
    part[q][f] = accy;
    __syncthreads();
    if (tid < 256) out[bb * (2 * F_) + F_ + f] = part[0][f] + part[1][f];
    __syncthreads();
  }
}

// ---------------------------------------------------------------------------
extern "C" void kernel_launch(void* const* d_in, const int* in_sizes, int n_in,
                              void* d_out, int out_size, void* d_ws, size_t ws_size,
                              hipStream_t stream) {
  (void)in_sizes; (void)n_in; (void)out_size; (void)ws_size;
  const float* x  = (const float*)d_in[0];
  const float* y  = (const float*)d_in[1];
  const float* Uw = (const float*)d_in[2];
  const float* Ub = (const float*)d_in[3];
  const float* Ww = (const float*)d_in[4];
  // d_in[5] (W_b) unused: max/softmax pipeline is shift-invariant.

  float* rowminS  = (float*)d_ws;                    // [B][N]      1024 f
  float* cpartS   = rowminS + B_ * N_;               // [B][32][M] 65536 f
  unsigned* cnt   = (unsigned*)(cpartS + B_ * 32 * M_);
  float* outp     = (float*)d_out;

  hipMemsetAsync(cnt, 0, sizeof(unsigned), stream);
  fused_all<<<dim3(256), dim3(512), 0, stream>>>(x, y, Uw, Ub, Ww,
                                                 rowminS, cpartS, cnt, outp);
}

// Round 8
// 82.422 us; speedup vs baseline: 2.1209x; 2.1209x over previous
//
#include <hip/hip_runtime.h>
#include <math.h>

#define B_ 8
#define N_ 128
#define M_ 256
#define F_ 256

#define LOG2E2 2.8853900817779268f  // 2*log2(e)

// ---------------------------------------------------------------------------
// KA: fused u-recompute + bilinear-tanh reduction partials.
// Grid (mg 0..3, ns 0..15, b 0..7) = 512 blocks (2/CU), 512 threads.
// Block owns n rows n0=ns*8..+7, m columns m0=mg*64..+63, all 256 f.
//   wave w = f-chunk fc (32 f);  lane = m offset.
//
// A1: us[r][g] = (x[n0+r,:].Uw[g,:] + Ub[g])*2log2e in LDS.
//     512 threads: g = tid&255, row-half rp = (tid>>8)*4 (4 rows each).
//     x rows wave-uniform -> s_load; Uw per-lane coalesced.
// A2: S[n][m] = sum_f Ww[f]*rcp(exp2(us[n][f]*y[m][f])+1)
//     y chunk in registers (yv[8] float4 = 32 VGPR), Ww chunk wave-uniform
//     -> SGPR, us via wave-uniform LDS broadcast reads.
//     alpha = Wsum - 2S is monotone-DECREASING in S => reduce MIN of S;
//     Wsum and W_b cancel in max/softmax (shift-invariance). EXACT.
// Partials: rminp[b][mg][n] (min over 64 m), cminp[b][ns][m] (min over 8 n).
// ---------------------------------------------------------------------------
__global__ __launch_bounds__(512, 4) void ka_alpha(
    const float* __restrict__ x, const float* __restrict__ y,
    const float* __restrict__ Uw, const float* __restrict__ Ub,
    const float* __restrict__ Ww,
    float* __restrict__ rminp, float* __restrict__ cminp) {
  __shared__ float us[8][F_];        //  8 KB
  __shared__ float red[8][8][64];    // 16 KB  [n][fc][m-lane]
  __shared__ float sm[8][64];        //  2 KB

  const int tid  = threadIdx.x;
  const int mg   = blockIdx.x;   // 0..3
  const int ns   = blockIdx.y;   // 0..15
  const int b    = blockIdx.z;   // 0..7
  const int n0   = ns * 8;
  const int m0   = mg * 64;
  const int lane = tid & 63;
  const int w    = tid >> 6;
  const int fc   = __builtin_amdgcn_readfirstlane(w);   // 0..7 (32 f each)

  // ---- A1: recompute this block's 8 u rows into LDS ----
  {
    const int g  = tid & 255;
    const int rp = (tid >> 8) * 4;   // 0 or 4
    const float* __restrict__ uwr = Uw + (size_t)g * F_;
    const float* __restrict__ xr  = x + (size_t)(b * N_ + n0 + rp) * F_;
    float a0 = 0.f, a1 = 0.f, a2 = 0.f, a3 = 0.f;
#pragma unroll 4
    for (int f = 0; f < F_; f += 4) {
      const float4 wv = *(const float4*)&uwr[f];           // per-lane
      const float4 x0 = *(const float4*)&xr[0 * F_ + f];   // uniform -> s_load
      const float4 x1 = *(const float4*)&xr[1 * F_ + f];
      const float4 x2 = *(const float4*)&xr[2 * F_ + f];
      const float4 x3 = *(const float4*)&xr[3 * F_ + f];
      a0 = fmaf(wv.x, x0.x, a0); a0 = fmaf(wv.y, x0.y, a0);
      a0 = fmaf(wv.z, x0.z, a0); a0 = fmaf(wv.w, x0.w, a0);
      a1 = fmaf(wv.x, x1.x, a1); a1 = fmaf(wv.y, x1.y, a1);
      a1 = fmaf(wv.z, x1.z, a1); a1 = fmaf(wv.w, x1.w, a1);
      a2 = fmaf(wv.x, x2.x, a2); a2 = fmaf(wv.y, x2.y, a2);
      a2 = fmaf(wv.z, x2.z, a2); a2 = fmaf(wv.w, x2.w, a2);
      a3 = fmaf(wv.x, x3.x, a3); a3 = fmaf(wv.y, x3.y, a3);
      a3 = fmaf(wv.z, x3.z, a3); a3 = fmaf(wv.w, x3.w, a3);
    }
    const float ubv = Ub[g];
    us[rp + 0][g] = (a0 + ubv) * LOG2E2;
    us[rp + 1][g] = (a1 + ubv) * LOG2E2;
    us[rp + 2][g] = (a2 + ubv) * LOG2E2;
    us[rp + 3][g] = (a3 + ubv) * LOG2E2;
  }

  // ---- stage y chunk (registers) + Ww chunk (wave-uniform -> SGPR) ----
  float4 yv[8];     // 32 VGPR
  float4 wwv[8];    // uniform
  {
    const float* yr = y + ((size_t)(b * M_ + m0 + lane)) * F_ + fc * 32;
    const float* wr = Ww + fc * 32;
#pragma unroll
    for (int j = 0; j < 8; ++j) {
      yv[j]  = *(const float4*)&yr[4 * j];
      wwv[j] = *(const float4*)&wr[4 * j];
    }
  }
  __syncthreads();

  // ---- A2: hot loop (LDS broadcast + registers only) ----
  float acc[8];
#pragma unroll
  for (int n = 0; n < 8; ++n) {
    float s0 = 0.f, s1 = 0.f;
#pragma unroll
    for (int j = 0; j < 8; ++j) {
      const float4 uv = *(const float4*)&us[n][fc * 32 + 4 * j]; // broadcast
      s0 = fmaf(wwv[j].x, __builtin_amdgcn_rcpf(__builtin_amdgcn_exp2f(uv.x * yv[j].x) + 1.f), s0);
      s1 = fmaf(wwv[j].y, __builtin_amdgcn_rcpf(__builtin_amdgcn_exp2f(uv.y * yv[j].y) + 1.f), s1);
      s0 = fmaf(wwv[j].z, __builtin_amdgcn_rcpf(__builtin_amdgcn_exp2f(uv.z * yv[j].z) + 1.f), s0);
      s1 = fmaf(wwv[j].w, __builtin_amdgcn_rcpf(__builtin_amdgcn_exp2f(uv.w * yv[j].w) + 1.f), s1);
    }
    acc[n] = s0 + s1;
  }

  // ---- cross-fc sum ----
#pragma unroll
  for (int n = 0; n < 8; ++n) red[n][fc][lane] = acc[n];
  __syncthreads();

  // wave w finalizes n = w over its 64 m-lanes
  float S = 0.f;
#pragma unroll
  for (int k = 0; k < 8; ++k) S += red[w][k][lane];

  // row-min partial (over this block's 64 m)
  float r = S;
#pragma unroll
  for (int s = 32; s; s >>= 1) r = fminf(r, __shfl_xor(r, s));
  if (lane == 0) rminp[((size_t)b * 4 + mg) * N_ + n0 + w] = r;

  // col-min partial (over this block's 8 n)
  sm[w][lane] = S;
  __syncthreads();
  if (w == 0) {
    float c = sm[0][lane];
#pragma unroll
    for (int k = 1; k < 8; ++k) c = fminf(c, sm[k][lane]);
    cminp[((size_t)b * 16 + ns) * M_ + m0 + lane] = c;
  }
}

// ---------------------------------------------------------------------------
// KB: finish. Grid (b, task): task 0 = x-softmax+x-pool, 1 = y-softmax+y-pool.
// Softmax inputs are -2 * min-partials (exact, shift-invariant).
// ---------------------------------------------------------------------------
__global__ __launch_bounds__(1024) void kb_final(
    const float* __restrict__ x, const float* __restrict__ y,
    const float* __restrict__ rminp, const float* __restrict__ cminp,
    float* __restrict__ out) {
  const int b = blockIdx.x;
  const int task = blockIdx.y;
  const int tid = threadIdx.x;
  const int wv = tid >> 6;
  __shared__ float wgt[M_];
  __shared__ float red[16];
  __shared__ float part[4][256];

  if (task == 0) {
    // ---- x attention over n of (-2 * min_m S) ----
    float rv = -INFINITY;
    if (tid < N_) {
      float v = INFINITY;
#pragma unroll
      for (int mg = 0; mg < 4; ++mg)
        v = fminf(v, rminp[((size_t)b * 4 + mg) * N_ + tid]);
      rv = -2.f * v;
    }
    float m1 = rv;
#pragma unroll
    for (int s = 32; s; s >>= 1) m1 = fmaxf(m1, __shfl_xor(m1, s));
    if ((tid & 63) == 0) red[wv] = m1;
    __syncthreads();
    m1 = red[0];
#pragma unroll
    for (int k = 1; k < 16; ++k) m1 = fmaxf(m1, red[k]);
    __syncthreads();
    const float e1 = (tid < N_) ? __expf(rv - m1) : 0.f;
    float s1 = e1;
#pragma unroll
    for (int s = 32; s; s >>= 1) s1 += __shfl_xor(s1, s);
    if ((tid & 63) == 0) red[wv] = s1;
    __syncthreads();
    s1 = 0.f;
#pragma unroll
    for (int k = 0; k < 16; ++k) s1 += red[k];
    if (tid < N_) wgt[tid] = e1 / s1;
    __syncthreads();

    const int q = tid >> 8, f = tid & 255;
    float accx = 0.f;
#pragma unroll 4
    for (int n = q; n < N_; n += 4)
      accx = fmaf(wgt[n], x[(size_t)(b * N_ + n) * F_ + f], accx);
    part[q][f] = accx;
    __syncthreads();
    if (tid < 256)
      out[b * (2 * F_) + f] = part[0][f] + part[1][f] + part[2][f] + part[3][f];
  } else {
    // ---- y attention over m of (-2 * min_n S) ----
    float cv = -INFINITY;
    if (tid < M_) {
      float c = INFINITY;
#pragma unroll
      for (int ns = 0; ns < 16; ++ns)
        c = fminf(c, cminp[((size_t)b * 16 + ns) * M_ + tid]);
      cv = -2.f * c;
    }
    float m2 = cv;
#pragma unroll
    for (int s = 32; s; s >>= 1) m2 = fmaxf(m2, __shfl_xor(m2, s));
    if ((tid & 63) == 0) red[wv] = m2;
    __syncthreads();
    m2 = red[0];
#pragma unroll
    for (int k = 1; k < 16; ++k) m2 = fmaxf(m2, red[k]);
    __syncthreads();
    const float e2 = (tid < M_) ? __expf(cv - m2) : 0.f;
    float s2 = e2;
#pragma unroll
    for (int s = 32; s; s >>= 1) s2 += __shfl_xor(s2, s);
    if ((tid & 63) == 0) red[wv] = s2;
    __syncthreads();
    s2 = 0.f;
#pragma unroll
    for (int k = 0; k < 16; ++k) s2 += red[k];
    if (tid < M_) wgt[tid] = e2 / s2;
    __syncthreads();

    const int q = tid >> 8, f = tid & 255;
    float accy = 0.f;
#pragma unroll 4
    for (int m = q; m < M_; m += 4)
      accy = fmaf(wgt[m], y[(size_t)(b * M_ + m) * F_ + f], accy);
    part[q][f] = accy;
    __syncthreads();
    if (tid < 256)
      out[b * (2 * F_) + F_ + f] =
          part[0][f] + part[1][f] + part[2][f] + part[3][f];
  }
}

// ---------------------------------------------------------------------------
extern "C" void kernel_launch(void* const* d_in, const int* in_sizes, int n_in,
                              void* d_out, int out_size, void* d_ws, size_t ws_size,
                              hipStream_t stream) {
  (void)in_sizes; (void)n_in; (void)out_size; (void)ws_size;
  const float* x  = (const float*)d_in[0];
  const float* y  = (const float*)d_in[1];
  const float* Uw = (const float*)d_in[2];
  const float* Ub = (const float*)d_in[3];
  const float* Ww = (const float*)d_in[4];
  // d_in[5] (W_b) unused: max/softmax pipeline is shift-invariant.

  float* rminp = (float*)d_ws;              // [B][4][N]    4096 f
  float* cminp = rminp + B_ * 4 * N_;       // [B][16][M]  32768 f
  float* outp  = (float*)d_out;

  ka_alpha<<<dim3(4, 16, B_), 512, 0, stream>>>(x, y, Uw, Ub, Ww, rminp, cminp);
  kb_final<<<dim3(B_, 2), 1024, 0, stream>>>(x, y, rminp, cminp, outp);
}

// Round 9
// 45.917 us; speedup vs baseline: 3.8070x; 1.7950x over previous
//
#include <hip/hip_runtime.h>
#include <math.h>

#define B_ 8
#define N_ 128
#define M_ 256
#define F_ 256

#define LOG2E2 2.8853900817779268f  // 2*log2(e)

// ---------------------------------------------------------------------------
// K1: u[r][g] = (x[r,:] . Uw[g,:] + Ub[g]) * 2log2e       r = b*N+n (1024 rows)
// ---------------------------------------------------------------------------
#define K1_BM 32
#define K1_BN 64
#define K1_BK 32

__global__ __launch_bounds__(256) void k1_gemm(const float* __restrict__ x,
                                               const float* __restrict__ Uw,
                                               const float* __restrict__ Ub,
                                               float* __restrict__ u) {
  __shared__ float As[K1_BK][K1_BM + 1];
  __shared__ float Bs[K1_BK][K1_BN + 1];
  const int tid  = threadIdx.x;
  const int row0 = blockIdx.x * K1_BM;
  const int col0 = blockIdx.y * K1_BN;
  const int tc = (tid & 15) * 4;
  const int tr = (tid >> 4) * 2;
  float acc[2][4] = {};

  for (int k0 = 0; k0 < F_; k0 += K1_BK) {
    {
      const int r = tid >> 3, c = (tid & 7) * 4;
      const float4 v = *(const float4*)&x[(row0 + r) * F_ + k0 + c];
      As[c + 0][r] = v.x; As[c + 1][r] = v.y; As[c + 2][r] = v.z; As[c + 3][r] = v.w;
    }
#pragma unroll
    for (int i0 = 0; i0 < 2; ++i0) {
      const int i = tid + i0 * 256;
      const int g = i >> 3, c = (i & 7) * 4;
      const float4 v = *(const float4*)&Uw[(col0 + g) * F_ + k0 + c];
      Bs[c + 0][g] = v.x; Bs[c + 1][g] = v.y; Bs[c + 2][g] = v.z; Bs[c + 3][g] = v.w;
    }
    __syncthreads();
#pragma unroll
    for (int k = 0; k < K1_BK; ++k) {
      const float a0 = As[k][tr], a1 = As[k][tr + 1];
      const float b0 = Bs[k][tc + 0], b1 = Bs[k][tc + 1];
      const float b2 = Bs[k][tc + 2], b3 = Bs[k][tc + 3];
      acc[0][0] = fmaf(a0, b0, acc[0][0]);
      acc[0][1] = fmaf(a0, b1, acc[0][1]);
      acc[0][2] = fmaf(a0, b2, acc[0][2]);
      acc[0][3] = fmaf(a0, b3, acc[0][3]);
      acc[1][0] = fmaf(a1, b0, acc[1][0]);
      acc[1][1] = fmaf(a1, b1, acc[1][1]);
      acc[1][2] = fmaf(a1, b2, acc[1][2]);
      acc[1][3] = fmaf(a1, b3, acc[1][3]);
    }
    __syncthreads();
  }
#pragma unroll
  for (int r = 0; r < 2; ++r) {
    float4 o;
    o.x = (acc[r][0] + Ub[col0 + tc + 0]) * LOG2E2;
    o.y = (acc[r][1] + Ub[col0 + tc + 1]) * LOG2E2;
    o.z = (acc[r][2] + Ub[col0 + tc + 2]) * LOG2E2;
    o.w = (acc[r][3] + Ub[col0 + tc + 3]) * LOG2E2;
    *(float4*)&u[(row0 + tr + r) * F_ + col0 + tc] = o;
  }
}

// ---------------------------------------------------------------------------
// K2 v7: occupancy-first, spill-free.
// Grid (mg 0..3, ns 0..15, b 0..7) = 512 blocks (2/CU), 512 threads (8 waves,
// 4 waves/SIMD).  NO __launch_bounds__ occupancy clamp (round-8 lesson:
// the min-waves arg caused a VGPR clamp -> scratch spill -> 82 us).
//   wave w = f-chunk fc (32 f);  lane = m offset within mg's 64 m.
// u rows staged once in LDS, hot-loop reads are same-address broadcasts
// (conflict-free); y chunk in yv[8] float4 (32 VGPR, static idx); Ww chunk
// wave-uniform. Accumulators are 8 NAMED scalars.
// S[n][m] = sum_f Ww[f]*rcp(exp2(us[n][f]*y[m][f])+1);  alpha = Wsum - 2S
// monotone-decreasing => reduce MIN of S (Wsum, W_b cancel in max/softmax).
// Partials: rminp[b][mg][n] (min over 64 m), cminp[b][ns][m] (min over 8 n).
// ---------------------------------------------------------------------------
__global__ void k2_alpha(const float* __restrict__ u,
                         const float* __restrict__ y,
                         const float* __restrict__ Ww,
                         float* __restrict__ rminp,
                         float* __restrict__ cminp) {
  __shared__ float us[8][F_];        //  8 KB
  __shared__ float red[8][8][64];    // 16 KB  [n][fc][m-lane]
  __shared__ float sm[8][64];        //  2 KB

  const int tid  = threadIdx.x;
  const int mg   = blockIdx.x;   // 0..3
  const int ns   = blockIdx.y;   // 0..15
  const int b    = blockIdx.z;   // 0..7
  const int n0   = ns * 8;
  const int m0   = mg * 64;
  const int lane = tid & 63;
  const int w    = tid >> 6;
  const int fc   = __builtin_amdgcn_readfirstlane(w);   // 0..7 (32 f each)

  // ---- stage this block's 8 u rows into LDS (coalesced, once) ----
  {
    const int r = tid >> 6, c = (tid & 63) * 4;
    *(float4*)&us[r][c] =
        *(const float4*)&u[(size_t)(b * N_ + n0 + r) * F_ + c];
  }

  // ---- per-thread y chunk (32 VGPR) + wave-uniform Ww chunk ----
  float4 yv[8];
  float4 wwv[8];
  {
    const float* yr = y + ((size_t)(b * M_ + m0 + lane)) * F_ + fc * 32;
    const float* wr = Ww + fc * 32;
#pragma unroll
    for (int j = 0; j < 8; ++j) {
      yv[j]  = *(const float4*)&yr[4 * j];
      wwv[j] = *(const float4*)&wr[4 * j];
    }
  }
  __syncthreads();

  // ---- hot loop: LDS broadcast + registers only ----
#define QUAD(nn, j, S0, S1)                                                              \
  do {                                                                                   \
    const float4 uv = *(const float4*)&us[nn][fc * 32 + 4 * (j)];                        \
    S0 = fmaf(wwv[j].x,                                                                  \
              __builtin_amdgcn_rcpf(__builtin_amdgcn_exp2f(uv.x * yv[j].x) + 1.f), S0);  \
    S1 = fmaf(wwv[j].y,                                                                  \
              __builtin_amdgcn_rcpf(__builtin_amdgcn_exp2f(uv.y * yv[j].y) + 1.f), S1);  \
    S0 = fmaf(wwv[j].z,                                                                  \
              __builtin_amdgcn_rcpf(__builtin_amdgcn_exp2f(uv.z * yv[j].z) + 1.f), S0);  \
    S1 = fmaf(wwv[j].w,                                                                  \
              __builtin_amdgcn_rcpf(__builtin_amdgcn_exp2f(uv.w * yv[j].w) + 1.f), S1);  \
  } while (0)

#define DO_N(nn, A)                                                                      \
  do {                                                                                   \
    float s0 = 0.f, s1 = 0.f;                                                            \
    QUAD(nn, 0, s0, s1); QUAD(nn, 1, s0, s1); QUAD(nn, 2, s0, s1); QUAD(nn, 3, s0, s1);  \
    QUAD(nn, 4, s0, s1); QUAD(nn, 5, s0, s1); QUAD(nn, 6, s0, s1); QUAD(nn, 7, s0, s1);  \
    A = s0 + s1;                                                                         \
  } while (0)

  float a0, a1, a2, a3, a4, a5, a6, a7;
  DO_N(0, a0); DO_N(1, a1); DO_N(2, a2); DO_N(3, a3);
  DO_N(4, a4); DO_N(5, a5); DO_N(6, a6); DO_N(7, a7);
#undef DO_N
#undef QUAD

  // ---- cross-fc sum ----
  red[0][fc][lane] = a0; red[1][fc][lane] = a1;
  red[2][fc][lane] = a2; red[3][fc][lane] = a3;
  red[4][fc][lane] = a4; red[5][fc][lane] = a5;
  red[6][fc][lane] = a6; red[7][fc][lane] = a7;
  __syncthreads();

  // wave w finalizes n = w over its 64 m-lanes
  float S = 0.f;
#pragma unroll
  for (int k = 0; k < 8; ++k) S += red[w][k][lane];

  // row-min partial (over this block's 64 m)
  float r = S;
#pragma unroll
  for (int s = 32; s; s >>= 1) r = fminf(r, __shfl_xor(r, s));
  if (lane == 0) rminp[((size_t)b * 4 + mg) * N_ + n0 + w] = r;

  // col-min partial (over this block's 8 n)
  sm[w][lane] = S;
  __syncthreads();
  if (w == 0) {
    float c = sm[0][lane];
#pragma unroll
    for (int k = 1; k < 8; ++k) c = fminf(c, sm[k][lane]);
    cminp[((size_t)b * 16 + ns) * M_ + m0 + lane] = c;
  }
}

// ---------------------------------------------------------------------------
// KB: finish. Grid (b, task): task 0 = x-softmax+x-pool, 1 = y-softmax+y-pool.
// Softmax inputs are -2 * min-partials (exact, shift-invariant).
// ---------------------------------------------------------------------------
__global__ __launch_bounds__(1024) void kb_final(
    const float* __restrict__ x, const float* __restrict__ y,
    const float* __restrict__ rminp, const float* __restrict__ cminp,
    float* __restrict__ out) {
  const int b = blockIdx.x;
  const int task = blockIdx.y;
  const int tid = threadIdx.x;
  const int wv = tid >> 6;
  __shared__ float wgt[M_];
  __shared__ float red[16];
  __shared__ float part[4][256];

  if (task == 0) {
    float rv = -INFINITY;
    if (tid < N_) {
      float v = INFINITY;
#pragma unroll
      for (int mg = 0; mg < 4; ++mg)
        v = fminf(v, rminp[((size_t)b * 4 + mg) * N_ + tid]);
      rv = -2.f * v;
    }
    float m1 = rv;
#pragma unroll
    for (int s = 32; s; s >>= 1) m1 = fmaxf(m1, __shfl_xor(m1, s));
    if ((tid & 63) == 0) red[wv] = m1;
    __syncthreads();
    m1 = red[0];
#pragma unroll
    for (int k = 1; k < 16; ++k) m1 = fmaxf(m1, red[k]);
    __syncthreads();
    const float e1 = (tid < N_) ? __expf(rv - m1) : 0.f;
    float s1 = e1;
#pragma unroll
    for (int s = 32; s; s >>= 1) s1 += __shfl_xor(s1, s);
    if ((tid & 63) == 0) red[wv] = s1;
    __syncthreads();
    s1 = 0.f;
#pragma unroll
    for (int k = 0; k < 16; ++k) s1 += red[k];
    if (tid < N_) wgt[tid] = e1 / s1;
    __syncthreads();

    const int q = tid >> 8, f = tid & 255;
    float accx = 0.f;
#pragma unroll 4
    for (int n = q; n < N_; n += 4)
      accx = fmaf(wgt[n], x[(size_t)(b * N_ + n) * F_ + f], accx);
    part[q][f] = accx;
    __syncthreads();
    if (tid < 256)
      out[b * (2 * F_) + f] = part[0][f] + part[1][f] + part[2][f] + part[3][f];
  } else {
    float cv = -INFINITY;
    if (tid < M_) {
      float c = INFINITY;
#pragma unroll
      for (int ns = 0; ns < 16; ++ns)
        c = fminf(c, cminp[((size_t)b * 16 + ns) * M_ + tid]);
      cv = -2.f * c;
    }
    float m2 = cv;
#pragma unroll
    for (int s = 32; s; s >>= 1) m2 = fmaxf(m2, __shfl_xor(m2, s));
    if ((tid & 63) == 0) red[wv] = m2;
    __syncthreads();
    m2 = red[0];
#pragma unroll
    for (int k = 1; k < 16; ++k) m2 = fmaxf(m2, red[k]);
    __syncthreads();
    const float e2 = (tid < M_) ? __expf(cv - m2) : 0.f;
    float s2 = e2;
#pragma unroll
    for (int s = 32; s; s >>= 1) s2 += __shfl_xor(s2, s);
    if ((tid & 63) == 0) red[wv] = s2;
    __syncthreads();
    s2 = 0.f;
#pragma unroll
    for (int k = 0; k < 16; ++k) s2 += red[k];
    if (tid < M_) wgt[tid] = e2 / s2;
    __syncthreads();

    const int q = tid >> 8, f = tid & 255;
    float accy = 0.f;
#pragma unroll 4
    for (int m = q; m < M_; m += 4)
      accy = fmaf(wgt[m], y[(size_t)(b * M_ + m) * F_ + f], accy);
    part[q][f] = accy;
    __syncthreads();
    if (tid < 256)
      out[b * (2 * F_) + F_ + f] =
          part[0][f] + part[1][f] + part[2][f] + part[3][f];
  }
}

// ---------------------------------------------------------------------------
extern "C" void kernel_launch(void* const* d_in, const int* in_sizes, int n_in,
                              void* d_out, int out_size, void* d_ws, size_t ws_size,
                              hipStream_t stream) {
  (void)in_sizes; (void)n_in; (void)out_size; (void)ws_size;
  const float* x  = (const float*)d_in[0];
  const float* y  = (const float*)d_in[1];
  const float* Uw = (const float*)d_in[2];
  const float* Ub = (const float*)d_in[3];
  const float* Ww = (const float*)d_in[4];
  // d_in[5] (W_b) unused: max/softmax pipeline is shift-invariant.

  float* u     = (float*)d_ws;                 // [B][N][F]    262144 f
  float* rminp = u + B_ * N_ * F_;             // [B][4][N]      4096 f
  float* cminp = rminp + B_ * 4 * N_;          // [B][16][M]   32768 f
  float* outp  = (float*)d_out;

  k1_gemm<<<dim3((B_ * N_) / K1_BM, F_ / K1_BN), 256, 0, stream>>>(x, Uw, Ub, u);
  k2_alpha<<<dim3(4, 16, B_), 512, 0, stream>>>(u, y, Ww, rminp, cminp);
  kb_final<<<dim3(B_, 2), 1024, 0, stream>>>(x, y, rminp, cminp, outp);
}